// Round 3
// baseline (1963.083 us; speedup 1.0000x reference)
//
#include <hip/hip_runtime.h>
#include <hip/hip_bf16.h>

// Causal SDPA fwd, fp32. Outputs concat in d_out: out [B,H,S,D] then p_attn [B,H,S,S].
// B=4 H=16 S=2048 D=64.
//
// Structure (R2 = R1 + nontemporal-store type fix):
//  - block = 256 thr (4 waves), 16 query rows/block, 4 rows/wave.
//  - Phase 1: K-tiles (128 rows) staged in LDS (stride 68 floats -> b128 at the
//    8-dword-per-bank floor), scores kept in regs (32/lane/row; reg i of tile
//    kt holds k = kt*128 + (i&1)*64 + lane), single QK pass, k-tile loop fully
//    unrolled so score reg indices are static (rule #20).
//  - softmax in regs + 64-lane shfl reduces; p_attn written once, normalized,
//    nontemporal dword stores; upper triangle = exact 0.0f (ref's exp(-1e9)
//    underflows to 0 too).
//  - Phase 2: V-tiles staged in same LDS; per-wave p chunk republished to
//    small LDS; PV with 4x16 (k-residue x d-quad) lane split, b128 V reads,
//    cross-lane reduce over lane bits 4..5.
//  - causal mask input ignored: tril by construction (k <= q enforced).

#define B_ 4
#define H_ 16
#define S_ 2048
#define D_ 64
#define RPB 16           // query rows per block
#define RPW 4            // query rows per wave
#define KT 128           // k rows per tile
#define NTILES (S_ / KT) // 16
#define LDK 68           // padded LDS stride (floats)

typedef float vfloat4 __attribute__((ext_vector_type(4)));  // clang vector: ok for nontemporal builtin

#define DOT4(S, QV, KV) \
  S = fmaf((QV).w, (KV).w, fmaf((QV).z, (KV).z, fmaf((QV).y, (KV).y, fmaf((QV).x, (KV).x, (S)))))

__device__ __forceinline__ void softmax_row_store(float (&s)[32], int qrow, int l,
                                                  float* __restrict__ prow) {
  float m = -1e30f;
  #pragma unroll
  for (int i = 0; i < 32; ++i) {
    int kg = (((i >> 1) << 7) + ((i & 1) << 6)) + l;
    if (kg <= qrow) m = fmaxf(m, s[i]);
  }
  #pragma unroll
  for (int off = 32; off; off >>= 1) m = fmaxf(m, __shfl_xor(m, off));
  float sum = 0.f;
  #pragma unroll
  for (int i = 0; i < 32; ++i) {
    int kg = (((i >> 1) << 7) + ((i & 1) << 6)) + l;
    float e = (kg <= qrow) ? __expf(s[i] - m) : 0.f;
    s[i] = e; sum += e;
  }
  #pragma unroll
  for (int off = 32; off; off >>= 1) sum += __shfl_xor(sum, off);
  float inv = 1.f / sum;
  #pragma unroll
  for (int i = 0; i < 32; ++i) {
    int kg = (((i >> 1) << 7) + ((i & 1) << 6)) + l;
    float pv = s[i] * inv;
    s[i] = pv;
    __builtin_nontemporal_store(pv, &prow[kg]);
  }
}

__global__ __launch_bounds__(256, 2)
void sdpa_causal_fp32(const float* __restrict__ Qg, const float* __restrict__ Kg,
                      const float* __restrict__ Vg, float* __restrict__ Og,
                      float* __restrict__ Pg) {
  __shared__ float tile[KT][LDK];    // K tile, then V tile (reused)
  __shared__ float qs[RPB][D_];      // pre-scaled Q rows
  __shared__ float ps[4][RPW][KT];   // per-wave p chunk for current tile

  const int tid = threadIdx.x;
  const int l   = tid & 63;
  const int w   = tid >> 6;
  const int bh  = blockIdx.y;
  const int q0  = blockIdx.x * RPB;
  const int nt  = (q0 >> 7) + 1;     // causal: tiles with base <= q0+15

  const float* Qb = Qg + (size_t)bh * S_ * D_;
  const float* Kb = Kg + (size_t)bh * S_ * D_;
  const float* Vb = Vg + (size_t)bh * S_ * D_;

  // ---- stage Q rows, folding scale = 1/sqrt(64) = 0.125 (256 thr, 1 float4 each)
  {
    int r  = tid >> 4;
    int d0 = (tid & 15) << 2;
    float4 qv = *(const float4*)(Qb + (size_t)(q0 + r) * D_ + d0);
    qv.x *= 0.125f; qv.y *= 0.125f; qv.z *= 0.125f; qv.w *= 0.125f;
    *(float4*)&qs[r][d0] = qv;
  }

  const int r0  = RPW * w;           // wave's first local row
  const int qra = q0 + r0;

  float s0[32], s1[32], s2[32], s3[32];  // reg i of tile kt: k = kt*128 + (i&1)*64 + l
  #pragma unroll
  for (int i = 0; i < 32; ++i) { s0[i] = 0.f; s1[i] = 0.f; s2[i] = 0.f; s3[i] = 0.f; }

  // =================== Phase 1: QK^T ===================
  #pragma unroll
  for (int kt = 0; kt < NTILES; ++kt) {
    if (kt < nt) {
      __syncthreads();
      const float4* src = (const float4*)(Kb + (size_t)kt * KT * D_);
      #pragma unroll
      for (int it = 0; it < (KT * D_ / 4) / 256; ++it) {  // 8 float4 per thread
        int idx = it * 256 + tid;
        *(float4*)&tile[idx >> 4][(idx & 15) << 2] = src[idx];
      }
      __syncthreads();
      #pragma unroll 2
      for (int db = 0; db < 16; ++db) {
        const int d0 = db << 2;
        float4 ka = *(const float4*)&tile[l][d0];        // k = kt*128 + l
        float4 kb = *(const float4*)&tile[l + 64][d0];   // k = kt*128 + 64 + l
        float4 qv0 = *(const float4*)&qs[r0 + 0][d0];    // broadcast reads
        float4 qv1 = *(const float4*)&qs[r0 + 1][d0];
        float4 qv2 = *(const float4*)&qs[r0 + 2][d0];
        float4 qv3 = *(const float4*)&qs[r0 + 3][d0];
        DOT4(s0[2*kt],   qv0, ka); DOT4(s0[2*kt+1], qv0, kb);
        DOT4(s1[2*kt],   qv1, ka); DOT4(s1[2*kt+1], qv1, kb);
        DOT4(s2[2*kt],   qv2, ka); DOT4(s2[2*kt+1], qv2, kb);
        DOT4(s3[2*kt],   qv3, ka); DOT4(s3[2*kt+1], qv3, kb);
      }
    }
  }

  // =================== softmax (in regs) + p_attn store ===================
  softmax_row_store(s0, qra + 0, l, Pg + (size_t)(bh * S_ + qra + 0) * S_);
  softmax_row_store(s1, qra + 1, l, Pg + (size_t)(bh * S_ + qra + 1) * S_);
  softmax_row_store(s2, qra + 2, l, Pg + (size_t)(bh * S_ + qra + 2) * S_);
  softmax_row_store(s3, qra + 3, l, Pg + (size_t)(bh * S_ + qra + 3) * S_);

  // =================== Phase 2: P @ V ===================
  float4 acc0 = {0.f,0.f,0.f,0.f}, acc1 = {0.f,0.f,0.f,0.f};
  float4 acc2 = {0.f,0.f,0.f,0.f}, acc3 = {0.f,0.f,0.f,0.f};
  const int kq  = l >> 4;            // k residue 0..3
  const int d0v = (l & 15) << 2;

  #pragma unroll
  for (int kt = 0; kt < NTILES; ++kt) {
    if (kt < nt) {
      __syncthreads();
      const float4* src = (const float4*)(Vb + (size_t)kt * KT * D_);
      #pragma unroll
      for (int it = 0; it < (KT * D_ / 4) / 256; ++it) {
        int idx = it * 256 + tid;
        *(float4*)&tile[idx >> 4][(idx & 15) << 2] = src[idx];
      }
      // publish this tile's p chunk (per-wave region)
      ps[w][0][l] = s0[2*kt]; ps[w][0][64 + l] = s0[2*kt + 1];
      ps[w][1][l] = s1[2*kt]; ps[w][1][64 + l] = s1[2*kt + 1];
      ps[w][2][l] = s2[2*kt]; ps[w][2][64 + l] = s2[2*kt + 1];
      ps[w][3][l] = s3[2*kt]; ps[w][3][64 + l] = s3[2*kt + 1];
      __syncthreads();
      #pragma unroll 4
      for (int kk = 0; kk < 32; ++kk) {
        int k = (kk << 2) | kq;
        float4 vv = *(const float4*)&tile[k][d0v];
        float pa = ps[w][0][k], pb = ps[w][1][k], pc = ps[w][2][k], pd = ps[w][3][k];
        acc0.x = fmaf(pa, vv.x, acc0.x); acc0.y = fmaf(pa, vv.y, acc0.y);
        acc0.z = fmaf(pa, vv.z, acc0.z); acc0.w = fmaf(pa, vv.w, acc0.w);
        acc1.x = fmaf(pb, vv.x, acc1.x); acc1.y = fmaf(pb, vv.y, acc1.y);
        acc1.z = fmaf(pb, vv.z, acc1.z); acc1.w = fmaf(pb, vv.w, acc1.w);
        acc2.x = fmaf(pc, vv.x, acc2.x); acc2.y = fmaf(pc, vv.y, acc2.y);
        acc2.z = fmaf(pc, vv.z, acc2.z); acc2.w = fmaf(pc, vv.w, acc2.w);
        acc3.x = fmaf(pd, vv.x, acc3.x); acc3.y = fmaf(pd, vv.y, acc3.y);
        acc3.z = fmaf(pd, vv.z, acc3.z); acc3.w = fmaf(pd, vv.w, acc3.w);
      }
    }
  }

  // reduce partial sums across the 4 k-residue groups (lane bits 4,5)
  #pragma unroll
  for (int off = 16; off <= 32; off <<= 1) {
    acc0.x += __shfl_xor(acc0.x, off); acc0.y += __shfl_xor(acc0.y, off);
    acc0.z += __shfl_xor(acc0.z, off); acc0.w += __shfl_xor(acc0.w, off);
    acc1.x += __shfl_xor(acc1.x, off); acc1.y += __shfl_xor(acc1.y, off);
    acc1.z += __shfl_xor(acc1.z, off); acc1.w += __shfl_xor(acc1.w, off);
    acc2.x += __shfl_xor(acc2.x, off); acc2.y += __shfl_xor(acc2.y, off);
    acc2.z += __shfl_xor(acc2.z, off); acc2.w += __shfl_xor(acc2.w, off);
    acc3.x += __shfl_xor(acc3.x, off); acc3.y += __shfl_xor(acc3.y, off);
    acc3.z += __shfl_xor(acc3.z, off); acc3.w += __shfl_xor(acc3.w, off);
  }
  if (kq == 0) {
    vfloat4 o0 = {acc0.x, acc0.y, acc0.z, acc0.w};
    vfloat4 o1 = {acc1.x, acc1.y, acc1.z, acc1.w};
    vfloat4 o2 = {acc2.x, acc2.y, acc2.z, acc2.w};
    vfloat4 o3 = {acc3.x, acc3.y, acc3.z, acc3.w};
    __builtin_nontemporal_store(o0, (vfloat4*)(Og + (size_t)(bh * S_ + qra + 0) * D_ + d0v));
    __builtin_nontemporal_store(o1, (vfloat4*)(Og + (size_t)(bh * S_ + qra + 1) * D_ + d0v));
    __builtin_nontemporal_store(o2, (vfloat4*)(Og + (size_t)(bh * S_ + qra + 2) * D_ + d0v));
    __builtin_nontemporal_store(o3, (vfloat4*)(Og + (size_t)(bh * S_ + qra + 3) * D_ + d0v));
  }
}

extern "C" void kernel_launch(void* const* d_in, const int* in_sizes, int n_in,
                              void* d_out, int out_size, void* d_ws, size_t ws_size,
                              hipStream_t stream) {
  (void)in_sizes; (void)n_in; (void)d_ws; (void)ws_size; (void)out_size;
  const float* q = (const float*)d_in[0];
  const float* k = (const float*)d_in[1];
  const float* v = (const float*)d_in[2];
  // d_in[3] = mask: known causal tril, enforced analytically (k <= q)
  float* out = (float*)d_out;
  float* p   = out + (size_t)B_ * H_ * S_ * D_;

  dim3 grid(S_ / RPB, B_ * H_);
  sdpa_causal_fp32<<<grid, 256, 0, stream>>>(q, k, v, out, p);
}